// Round 1
// 775.028 us; speedup vs baseline: 1.0688x; 1.0688x over previous
//
#include <hip/hip_runtime.h>
#include <stdint.h>

#define TMASK ((1u << 19) - 1u)
// Embeddings are uniform in [-1e-4, 1e-4]. Scale by 2^13 before fp16
// rounding so every value is a *normal* fp16 (no denormal-flush risk);
// power-of-2 scaling is exact, so added error is just fp16 rounding of
// the scaled value: <= 2^-13 * 2^-12 ~= 3e-8 absolute. Unscale once after
// the trilinear blend.
#define EMB_SCALE     8192.0f
#define EMB_INV_SCALE (1.0f / 8192.0f)

typedef float    vf2 __attribute__((ext_vector_type(2)));
typedef float    vf4 __attribute__((ext_vector_type(4)));
typedef _Float16 vh2 __attribute__((ext_vector_type(2)));
typedef _Float16 vh4 __attribute__((ext_vector_type(4)));

// grid_size = 2/res, fp32 correctly-rounded (compile-time folded), matching
// the reference's fp32 division. Resolutions: floor(16 * b^l), b = 32^(1/15).
static __device__ const float GS_F[16] = {
    2.0f/16.0f, 2.0f/20.0f, 2.0f/25.0f, 2.0f/32.0f,
    2.0f/40.0f, 2.0f/50.0f, 2.0f/64.0f, 2.0f/80.0f,
    2.0f/101.0f, 2.0f/128.0f, 2.0f/161.0f, 2.0f/203.0f,
    2.0f/256.0f, 2.0f/322.0f, 2.0f/406.0f, 2.0f/512.0f};
// res/2 — exact in fp32.
static __device__ const float INVGS_F[16] = {
    8.0f, 10.0f, 12.5f, 16.0f,
    20.0f, 25.0f, 32.0f, 40.0f,
    50.5f, 64.0f, 80.5f, 101.5f,
    128.0f, 161.0f, 203.0f, 256.0f};

struct Corner8 { vf2 e[8]; float w[8]; };

__device__ __forceinline__ vf2 load_entry(const vf2* __restrict__ tb, uint32_t h) {
    return tb[h];
}
__device__ __forceinline__ vf2 load_entry(const vh2* __restrict__ tb, uint32_t h) {
    const vh2 v = tb[h];            // one 4 B dword gather
    vf2 r; r.x = (float)v.x; r.y = (float)v.y;
    return r;
}

template <typename T>
__device__ __forceinline__ void gather_level(
    const T* __restrict__ tb, float cx, float cy, float cz,
    float gs, float ivg, Corner8& g)
{
    const float ux = (cx + 1.0f) * ivg;
    const float uy = (cy + 1.0f) * ivg;
    const float uz = (cz + 1.0f) * ivg;
    const float fx = floorf(ux), fy = floorf(uy), fz = floorf(uz);
    const int ix = (int)fx, iy = (int)fy, iz = (int)fz;
    const float wx = (cx - (fx * gs - 1.0f)) * ivg;
    const float wy = (cy - (fy * gs - 1.0f)) * ivg;
    const float wz = (cz - (fz * gs - 1.0f)) * ivg;

    const uint32_t px0 = (uint32_t)ix * 73856093u, px1 = px0 + 73856093u;
    const uint32_t py0 = (uint32_t)iy * 19349663u, py1 = py0 + 19349663u;
    const uint32_t pz0 = (uint32_t)iz * 83492791u, pz1 = pz0 + 83492791u;

    g.e[0] = load_entry(tb, (px0 ^ py0 ^ pz0) & TMASK);
    g.e[1] = load_entry(tb, (px0 ^ py0 ^ pz1) & TMASK);
    g.e[2] = load_entry(tb, (px0 ^ py1 ^ pz0) & TMASK);
    g.e[3] = load_entry(tb, (px0 ^ py1 ^ pz1) & TMASK);
    g.e[4] = load_entry(tb, (px1 ^ py0 ^ pz0) & TMASK);
    g.e[5] = load_entry(tb, (px1 ^ py0 ^ pz1) & TMASK);
    g.e[6] = load_entry(tb, (px1 ^ py1 ^ pz0) & TMASK);
    g.e[7] = load_entry(tb, (px1 ^ py1 ^ pz1) & TMASK);

    const float wxm = 1.0f - wx, wym = 1.0f - wy, wzm = 1.0f - wz;
    const float c00 = wxm * wym, c01 = wxm * wy;
    const float c10 = wx  * wym, c11 = wx  * wy;
    g.w[0] = c00 * wzm; g.w[1] = c00 * wz;
    g.w[2] = c01 * wzm; g.w[3] = c01 * wz;
    g.w[4] = c10 * wzm; g.w[5] = c10 * wz;
    g.w[6] = c11 * wzm; g.w[7] = c11 * wz;
}

__device__ __forceinline__ vf2 blend(const Corner8& g) {
    vf2 r;
    r.x = g.w[0]*g.e[0].x + g.w[1]*g.e[1].x + g.w[2]*g.e[2].x + g.w[3]*g.e[3].x
        + g.w[4]*g.e[4].x + g.w[5]*g.e[5].x + g.w[6]*g.e[6].x + g.w[7]*g.e[7].x;
    r.y = g.w[0]*g.e[0].y + g.w[1]*g.e[1].y + g.w[2]*g.e[2].y + g.w[3]*g.e[3].y
        + g.w[4]*g.e[4].y + g.w[5]*g.e[5].y + g.w[6]*g.e[6].y + g.w[7]*g.e[7].y;
    return r;
}

// fp32 [L][T][2] -> scaled fp16 [L][T][2]. Read 16 B (2 entries), write 8 B.
__global__ __launch_bounds__(256) void convert_kernel(
    const vf4* __restrict__ emb, vh4* __restrict__ tb, int n4)
{
    const int i = blockIdx.x * blockDim.x + threadIdx.x;
    if (i >= n4) return;
    const vf4 v = __builtin_nontemporal_load(emb + i);
    vh4 o;
    o.x = (_Float16)(v.x * EMB_SCALE);
    o.y = (_Float16)(v.y * EMB_SCALE);
    o.z = (_Float16)(v.z * EMB_SCALE);
    o.w = (_Float16)(v.w * EMB_SCALE);
    tb[i] = o;   // plain store: let the table live in L2/L3
}

// Two points per thread (split-half so both are lane-coalesced): 16
// outstanding divergent gathers per wave iteration for latency hiding.
// ws layout: [l][b] float2 (level-major, coalesced full-line stores).
template <typename T, bool SCALED>
__global__ __launch_bounds__(256) void level_kernel(
    const float* __restrict__ x,
    const T* __restrict__ tbl,
    vf2* __restrict__ ws,
    int B, int half, int l0, int l1)
{
    const int p0 = blockIdx.x * blockDim.x + threadIdx.x;
    if (p0 >= half) return;
    const int p1 = p0 + half;
    const bool has1 = p1 < B;
    const int p1c = has1 ? p1 : p0;

    // Nontemporal: streaming x must not evict the L2-resident table slice.
    const float ax = __builtin_nontemporal_load(x + 3*p0 + 0);
    const float ay = __builtin_nontemporal_load(x + 3*p0 + 1);
    const float az = __builtin_nontemporal_load(x + 3*p0 + 2);
    const float bx = __builtin_nontemporal_load(x + 3*p1c + 0);
    const float by = __builtin_nontemporal_load(x + 3*p1c + 1);
    const float bz = __builtin_nontemporal_load(x + 3*p1c + 2);

    const float cax = fminf(fmaxf(ax, -1.0f), 1.0f);
    const float cay = fminf(fmaxf(ay, -1.0f), 1.0f);
    const float caz = fminf(fmaxf(az, -1.0f), 1.0f);
    const float cbx = fminf(fmaxf(bx, -1.0f), 1.0f);
    const float cby = fminf(fmaxf(by, -1.0f), 1.0f);
    const float cbz = fminf(fmaxf(bz, -1.0f), 1.0f);

#pragma unroll 1
    for (int l = l0; l <= l1; ++l) {
        const float gs  = GS_F[l];
        const float ivg = INVGS_F[l];
        const T* __restrict__ tb = tbl + ((size_t)l << 19);

        Corner8 ga, gb;
        gather_level(tb, cax, cay, caz, gs, ivg, ga);
        gather_level(tb, cbx, cby, cbz, gs, ivg, gb);

        vf2 ra = blend(ga);
        vf2 rb = blend(gb);
        if constexpr (SCALED) {
            ra.x *= EMB_INV_SCALE; ra.y *= EMB_INV_SCALE;
            rb.x *= EMB_INV_SCALE; rb.y *= EMB_INV_SCALE;
        }

        __builtin_nontemporal_store(ra, &ws[(long)l * B + p0]);
        if (has1) __builtin_nontemporal_store(rb, &ws[(long)l * B + p1]);
    }
}

// ws [16][B] float2 -> out [B][8] float4, LDS-tiled so global writes are
// lane-consecutive float4s (full 64B lines per wave store).
__global__ __launch_bounds__(256) void transpose_kernel(
    const vf2* __restrict__ ws, vf4* __restrict__ out, int B)
{
    __shared__ vf2 tile[16][257];   // +1 pad: store-phase reads drop to <=2-way
    const int t = threadIdx.x;
    const int base = blockIdx.x * 256;

#pragma unroll
    for (int l = 0; l < 16; ++l) {
        const int b = base + t;
        if (b < B) tile[l][t] = __builtin_nontemporal_load(&ws[(long)l * B + b]);
    }
    __syncthreads();

#pragma unroll
    for (int k = 0; k < 8; ++k) {
        const int flat = k * 256 + t;        // float4 index within block's 2048
        const int p = flat >> 3;             // local point
        const int j = flat & 7;              // float4 slot within point
        if (base + p < B) {
            const vf2 a = tile[2*j][p];
            const vf2 c = tile[2*j+1][p];
            vf4 v; v.x = a.x; v.y = a.y; v.z = c.x; v.w = c.y;
            __builtin_nontemporal_store(v, &out[(long)base * 8 + flat]);
        }
    }
}

// Fallback (ws too small): direct scatter, one point per thread, fp32 tables.
__global__ __launch_bounds__(256) void level_scatter_kernel(
    const float* __restrict__ x,
    const float* __restrict__ emb,
    vf2* __restrict__ out,
    int B, int l0, int l1)
{
    const int b = blockIdx.x * blockDim.x + threadIdx.x;
    if (b >= B) return;
    const float cx = fminf(fmaxf(x[3*b+0], -1.0f), 1.0f);
    const float cy = fminf(fmaxf(x[3*b+1], -1.0f), 1.0f);
    const float cz = fminf(fmaxf(x[3*b+2], -1.0f), 1.0f);
#pragma unroll 1
    for (int l = l0; l <= l1; ++l) {
        const vf2* __restrict__ tb = ((const vf2*)emb) + ((size_t)l << 19);
        Corner8 g;
        gather_level(tb, cx, cy, cz, GS_F[l], INVGS_F[l], g);
        out[(long)b * 16 + l] = blend(g);
    }
}

extern "C" void kernel_launch(void* const* d_in, const int* in_sizes, int n_in,
                              void* d_out, int out_size, void* d_ws, size_t ws_size,
                              hipStream_t stream) {
    const float* x   = (const float*)d_in[0];
    const float* emb = (const float*)d_in[1];
    const int B = in_sizes[0] / 3;

    const size_t tbl_bytes = (size_t)16 * 524288 * sizeof(vh2);   // 32 MB fp16 tables
    const size_t wsl_bytes = (size_t)B * 16 * sizeof(vf2);        // level-major intermediate

    // Place the fp16 tables: preferably in d_ws after the intermediate;
    // otherwise stage them in d_out (dead storage until transpose overwrites it).
    vh2* tb = nullptr;
    vf2* ws = nullptr;
    if (ws_size >= tbl_bytes + wsl_bytes) {
        tb = (vh2*)d_ws;
        ws = (vf2*)((char*)d_ws + tbl_bytes);
    } else if (ws_size >= wsl_bytes && (size_t)out_size >= tbl_bytes) {
        tb = (vh2*)d_out;
        ws = (vf2*)d_ws;
    }

    if (tb) {
        const int n4 = 16 * 524288 * 2 / 4;   // 4,194,304 float4s of fp32 emb
        convert_kernel<<<(n4 + 255) / 256, 256, 0, stream>>>(
            (const vf4*)emb, (vh4*)tb, n4);

        const int half = (B + 1) / 2;
        const int grid = (half + 255) / 256;
        // Levels 0-4: combined fp16 line footprint ~3.1 MB -> fits one XCD L2.
        level_kernel<vh2, true><<<grid, 256, 0, stream>>>(x, tb, ws, B, half, 0, 4);
        // Levels 5-15: one launch each; 2 MB fp16 slice is L2-resident with headroom.
        for (int l = 5; l < 16; ++l)
            level_kernel<vh2, true><<<grid, 256, 0, stream>>>(x, tb, ws, B, half, l, l);
        transpose_kernel<<<(B + 255) / 256, 256, 0, stream>>>(ws, (vf4*)d_out, B);
    } else if (ws_size >= wsl_bytes) {
        // fp32 path (previous best): no room for fp16 tables anywhere.
        vf2* wsd = (vf2*)d_ws;
        const int half = (B + 1) / 2;
        const int grid = (half + 255) / 256;
        level_kernel<vf2, false><<<grid, 256, 0, stream>>>(
            x, (const vf2*)emb, wsd, B, half, 0, 5);
        for (int l = 6; l < 16; ++l)
            level_kernel<vf2, false><<<grid, 256, 0, stream>>>(
                x, (const vf2*)emb, wsd, B, half, l, l);
        transpose_kernel<<<(B + 255) / 256, 256, 0, stream>>>(wsd, (vf4*)d_out, B);
    } else {
        const int grid = (B + 255) / 256;
        vf2* o = (vf2*)d_out;
        level_scatter_kernel<<<grid, 256, 0, stream>>>(x, emb, o, B, 0, 5);
        for (int l = 6; l < 16; ++l)
            level_scatter_kernel<<<grid, 256, 0, stream>>>(x, emb, o, B, l, l);
    }
}